// Round 10
// baseline (469.100 us; speedup 1.0000x reference)
//
#include <hip/hip_runtime.h>
#include <hip/hip_bf16.h>
#include <float.h>

#define K_NEI 9
#define M 4096
#define N 65536
#define D 128
#define SEGS 32
#define SEG_LEN (N / SEGS)     // 2048 bank rows per segment
#define QB 128                 // queries per block
#define BB 32                  // bank rows per chunk (per wave, private)
#define CHUNKS (SEG_LEN / BB)  // 64
#define QGROUPS (M / QB)       // 32

typedef __bf16 bf16x8 __attribute__((ext_vector_type(8)));
typedef float floatx4 __attribute__((ext_vector_type(4)));

static __device__ inline floatx4 mfma16(bf16x8 a, bf16x8 b, floatx4 c) {
    return __builtin_amdgcn_mfma_f32_16x16x32_bf16(a, b, c, 0, 0, 0);
}

// ---- sorted-9 toolkit -----------------------------------------------------
static __device__ inline void ce(float& a, float& b) {
    float lo = fminf(a, b), hi = fmaxf(a, b); a = lo; b = hi;
}
// canonical optimal 25-CE / depth-7 sorting network for 9 (ascending)
static __device__ inline void sort9(float t[K_NEI]) {
    ce(t[0],t[3]); ce(t[1],t[7]); ce(t[2],t[5]); ce(t[4],t[8]);
    ce(t[0],t[7]); ce(t[2],t[4]); ce(t[3],t[8]); ce(t[5],t[6]);
    ce(t[0],t[2]); ce(t[1],t[3]); ce(t[4],t[5]); ce(t[7],t[8]);
    ce(t[1],t[4]); ce(t[3],t[6]); ce(t[5],t[7]);
    ce(t[0],t[1]); ce(t[2],t[4]); ce(t[3],t[5]); ce(t[6],t[8]);
    ce(t[2],t[3]); ce(t[4],t[5]); ce(t[6],t[7]);
    ce(t[1],t[2]); ce(t[3],t[4]); ce(t[5],t[6]);
}
// t, o sorted ascending -> t = sorted 9 smallest of union (bitonic min trick)
static __device__ inline void merge9(float t[K_NEI], const float o[K_NEI]) {
    float m[K_NEI];
#pragma unroll
    for (int i = 0; i < K_NEI; ++i) m[i] = fminf(t[i], o[K_NEI - 1 - i]);
    sort9(m);
#pragma unroll
    for (int i = 0; i < K_NEI; ++i) t[i] = m[i];
}
// pool the 4 partner lanes (lane ^16, ^32): all 4 end with identical exact
// top-9 of the quad's union. ONLY valid if the 4 lists are element-disjoint.
static __device__ inline void quad_merge(float t[K_NEI]) {
    float o[K_NEI];
#pragma unroll
    for (int i = 0; i < K_NEI; ++i) o[i] = __shfl_xor(t[i], 16, 64);
    merge9(t, o);
#pragma unroll
    for (int i = 0; i < K_NEI; ++i) o[i] = __shfl_xor(t[i], 32, 64);
    merge9(t, o);
}

// ---------------------------------------------------------------------------
// Kernel 1 (fused prep): fp32 -> bf16 convert + row norms for BOTH inputs,
// plus per-call init of thr_g (gates) and done (qgroup counters) -- ws is
// re-poisoned 0xAA before every timed call.
// ---------------------------------------------------------------------------
__global__ void prep_kernel(const float* __restrict__ bank,
                            const float* __restrict__ feats,
                            __hip_bfloat16* __restrict__ bankbf,
                            __hip_bfloat16* __restrict__ featbf,
                            float* __restrict__ bsqn,
                            float* __restrict__ qsq,
                            int* __restrict__ thr_g,
                            int* __restrict__ done) {
    int row  = (int)((blockIdx.x * blockDim.x + threadIdx.x) >> 6);
    int lane = threadIdx.x & 63;
    if (row >= N + M) return;
    const float* src = (row < N) ? (bank + (size_t)row * D)
                                 : (feats + (size_t)(row - N) * D);
    __hip_bfloat16* dst = (row < N) ? (bankbf + (size_t)row * D)
                                    : (featbf + (size_t)(row - N) * D);
    float2 v = ((const float2*)src)[lane];
    float s = v.x * v.x + v.y * v.y;
    dst[lane * 2 + 0] = __float2bfloat16(v.x);
    dst[lane * 2 + 1] = __float2bfloat16(v.y);
#pragma unroll
    for (int off = 32; off > 0; off >>= 1) s += __shfl_down(s, off, 64);
    if (lane == 0) {
        if (row < N) {
            bsqn[row] = -0.5f * s;
        } else {
            qsq[row - N] = s;
            thr_g[row - N] = 0x7f7f7f7f;   // 3.39e38f
        }
    }
    if (lane == 1 && row >= N && row < N + QGROUPS) done[row - N] = 0;
}

// ---------------------------------------------------------------------------
// Kernel 2: BARRIER-FREE MFMA distance + fused top-9 + fused final merge.
//
// ROUNDS 2..9 LESSON: since round 2 the kernel has been STALL-bound, not
// VALU-bound (361 us: VALU 30%, MFMA 7.6%, ~65% idle). The per-chunk
// __syncthreads + vmcnt(0) drain serialized 4 data-dependent waves 32x per
// block at ~2 blocks/CU. THIS ROUND removes the shared LDS tile and ALL
// K-loop barriers: each wave loads its bank fragments DIRECTLY into VGPRs
// (same per-lane addresses the GL_LDS staging used -- it was an identity
// copy), software-pipelined one chunk ahead in rotating register buffers.
// Ordinary loads => the compiler's waitcnt pass emits fine-grained
// vmcnt(N>0) waits (AITER-style, never a full drain). Cost: bank reads are
// 4x redundant per block (~2 GB from L2, ~60 us floor) -- acceptable vs the
// removed stall. __launch_bounds__(256,2): 256-reg budget for ~172 live
// (afc+afn 64, qf 32, acc 16, t9 18, misc) -- zero spill (rounds 7/8).
// XCD-swizzled: seg%8 == blockIdx%8, each XCD's ~2 MB working set is
// L2-resident.
//
// acc init = -0.5*bs (fp32) => acc = dot - 0.5*bs => d2 = qs - 2*acc.
// Gate: d2 <= g  <=>  acc >= h = 0.5*(qs - g): 1 reg-max + 1 v_cmp per 4
// elements. Gate-merge events (ch = 0,1,3,7,15,31,47 of 64): each 4-lane
// quad computes its EXACT pooled top-9 (disjoint lists: leader keeps,
// followers clear -- round-5 bug) and publishes the pooled 9th (atomicMin,
// dirty-skip). Last seg-block per qgroup folds the 32 sorted lists.
// ---------------------------------------------------------------------------
__global__ __launch_bounds__(256, 2)
void knn_main(const __hip_bfloat16* __restrict__ bankbf,
              const __hip_bfloat16* __restrict__ featbf,
              const float* __restrict__ bsqn,
              const float* __restrict__ qsqp,
              int* __restrict__ thr_g,
              float* __restrict__ part,
              int* __restrict__ done,
              float* __restrict__ out) {
    __shared__ int sm_last;

    const int tid  = threadIdx.x;
    const int lane = tid & 63;
    const int wv   = tid >> 6;
    // XCD swizzle: seg%8 == blockIdx%8
    const int s8  = blockIdx.x & 7;
    const int t_  = blockIdx.x >> 3;
    const int bq  = t_ & 31;
    const int seg = ((t_ >> 5) << 3) | s8;
    const int qbase  = bq * QB;
    const int cbase0 = seg * SEG_LEN;
    const int l15 = lane & 15, l4 = lane >> 4;

    // query fragments (B operand): wave wv owns queries wv*32 .. wv*32+31
    bf16x8 qf[2][4];
    float qs4[2];
    int qglob[2];
#pragma unroll
    for (int qt = 0; qt < 2; ++qt) {
        int q = qbase + wv * 32 + qt * 16 + l15;
        qglob[qt] = q;
        qs4[qt]   = qsqp[q];
#pragma unroll
        for (int ks = 0; ks < 4; ++ks)
            qf[qt][ks] = *(const bf16x8*)(featbf + (size_t)q * D + ks * 32 + l4 * 8);
    }

    float t9[2][K_NEI];
    float g[2], lastpub[2];
#pragma unroll
    for (int qt = 0; qt < 2; ++qt) {
        g[qt] = FLT_MAX;
        lastpub[qt] = FLT_MAX;
#pragma unroll
        for (int j = 0; j < K_NEI; ++j) t9[qt][j] = FLT_MAX;
    }

    const __hip_bfloat16* segp = bankbf + (size_t)cbase0 * D;
    const int fo = l15 * D + l4 * 8;   // lane's fragment offset within a tile

    // prologue: load chunk 0 fragments + norms + gates into registers
    bf16x8 afc[2][4];
#pragma unroll
    for (int bt = 0; bt < 2; ++bt)
#pragma unroll
        for (int ks = 0; ks < 4; ++ks)
            afc[bt][ks] = *(const bf16x8*)(segp + (size_t)bt * 16 * D + fo + ks * 32);
    floatx4 nsc[2];
#pragma unroll
    for (int bt = 0; bt < 2; ++bt)
        nsc[bt] = *(const floatx4*)&bsqn[cbase0 + bt * 16 + l4 * 4];
    int tgc[2];
#pragma unroll
    for (int qt = 0; qt < 2; ++qt)
        tgc[qt] = __hip_atomic_load(&thr_g[qglob[qt]], __ATOMIC_RELAXED,
                                    __HIP_MEMORY_SCOPE_AGENT);

#pragma unroll 2
    for (int ch = 0; ch < CHUNKS; ++ch) {
        // prefetch chunk ch+1 (registers; compiler pipelines via vmcnt(N))
        bf16x8 afn[2][4];
        floatx4 nsn[2];
        int tgn[2];
        if (ch + 1 < CHUNKS) {
            const __hip_bfloat16* p1 = segp + (size_t)(ch + 1) * BB * D;
#pragma unroll
            for (int bt = 0; bt < 2; ++bt)
#pragma unroll
                for (int ks = 0; ks < 4; ++ks)
                    afn[bt][ks] = *(const bf16x8*)(p1 + (size_t)bt * 16 * D + fo + ks * 32);
#pragma unroll
            for (int bt = 0; bt < 2; ++bt)
                nsn[bt] = *(const floatx4*)&bsqn[cbase0 + (ch + 1) * BB + bt * 16 + l4 * 4];
#pragma unroll
            for (int qt = 0; qt < 2; ++qt)
                tgn[qt] = __hip_atomic_load(&thr_g[qglob[qt]], __ATOMIC_RELAXED,
                                            __HIP_MEMORY_SCOPE_AGENT);
        }

        // acc init = -0.5*bs (D-layout row = l4*4+r)
        floatx4 acc[2][2];
#pragma unroll
        for (int bt = 0; bt < 2; ++bt)
#pragma unroll
            for (int qt = 0; qt < 2; ++qt) acc[bt][qt] = nsc[bt];
        // MFMA: 2 bank-tiles x 2 query-tiles, K = 128 (4 ksteps of 32)
#pragma unroll
        for (int ks = 0; ks < 4; ++ks)
#pragma unroll
            for (int bt = 0; bt < 2; ++bt)
#pragma unroll
                for (int qt = 0; qt < 2; ++qt)
                    acc[bt][qt] = mfma16(afc[bt][ks], qf[qt][ks], acc[bt][qt]);

        // gates -> thresholds on raw acc (loosening guards transform rounding)
        float h[2];
#pragma unroll
        for (int qt = 0; qt < 2; ++qt) {
            g[qt] = fminf(g[qt], __int_as_float(tgc[qt]));
            h[qt] = 0.5f * (qs4[qt] - g[qt] * 1.0000005f);
        }

        // selection: 1 reg-max + 1 v_cmp per 4 elements; rare insert path
#pragma unroll
        for (int bt = 0; bt < 2; ++bt) {
#pragma unroll
            for (int qt = 0; qt < 2; ++qt) {
                float a0 = acc[bt][qt][0], a1 = acc[bt][qt][1];
                float a2 = acc[bt][qt][2], a3 = acc[bt][qt][3];
                float mx = fmaxf(fmaxf(a0, a1), fmaxf(a2, a3));
                if (__ballot(mx >= h[qt])) {
#pragma unroll
                    for (int r = 0; r < 4; ++r) {
                        float a = acc[bt][qt][r];
                        if (a >= h[qt]) {
                            float d2 = fmaxf(fmaf(-2.f, a, qs4[qt]), 0.f);
                            if (d2 <= g[qt]) {
                                t9[qt][K_NEI - 1] = d2;
#pragma unroll
                                for (int s = K_NEI - 1; s > 0; --s)
                                    ce(t9[qt][s - 1], t9[qt][s]);
                                g[qt] = fminf(g[qt], t9[qt][K_NEI - 1]);
                            }
                        }
                    }
                }
            }
        }
        // gate-merge events (ch = 0,1,3,7,15,31,47 -> 64-bit mask):
        // exact quad pool -> publish 9th; leader keeps, followers clear.
        if ((0x80008000808BULL >> ch) & 1ULL) {
#pragma unroll
            for (int qt = 0; qt < 2; ++qt) {
                quad_merge(t9[qt]);
                float nth = t9[qt][K_NEI - 1];
                g[qt] = fminf(g[qt], nth);
                if (l4 == 0) {
                    if (nth < lastpub[qt]) {
                        atomicMin(&thr_g[qglob[qt]], __float_as_int(nth));
                        lastpub[qt] = nth;
                    }
                } else {
                    // follower: reset so lists stay element-disjoint
#pragma unroll
                    for (int j = 0; j < K_NEI; ++j) t9[qt][j] = FLT_MAX;
                }
            }
        }
        // rotate pipeline registers (unroll-2 eliminates the copies)
#pragma unroll
        for (int bt = 0; bt < 2; ++bt) {
#pragma unroll
            for (int ks = 0; ks < 4; ++ks) afc[bt][ks] = afn[bt][ks];
            nsc[bt] = nsn[bt];
        }
#pragma unroll
        for (int qt = 0; qt < 2; ++qt) tgc[qt] = tgn[qt];
    }

    // ---- epilogue: quad pool (disjoint) = exact block top-9 per query -----
#pragma unroll
    for (int qt = 0; qt < 2; ++qt) quad_merge(t9[qt]);
    if (l4 == 0) {
#pragma unroll
        for (int qt = 0; qt < 2; ++qt) {
            float* dst = part + ((size_t)qglob[qt] * SEGS + seg) * K_NEI;
#pragma unroll
            for (int j = 0; j < K_NEI; ++j) dst[j] = t9[qt][j];
        }
    }

    // ---- fused final: last seg-block of this qgroup folds 32 sorted lists --
    __threadfence();            // release our part writes device-wide
    __syncthreads();
    if (tid == 0)
        sm_last = (atomicAdd(&done[bq], 1) == SEGS - 1) ? 1 : 0;
    __syncthreads();
    if (sm_last && tid < QB) {
        int q = qbase + tid;
        const float* p = part + (size_t)q * SEGS * K_NEI;
        float R[K_NEI], nx[K_NEI];
#pragma unroll
        for (int j = 0; j < K_NEI; ++j)
            R[j] = __hip_atomic_load(p + j, __ATOMIC_RELAXED,
                                     __HIP_MEMORY_SCOPE_AGENT);
#pragma unroll
        for (int j = 0; j < K_NEI; ++j)
            nx[j] = __hip_atomic_load(p + K_NEI + j, __ATOMIC_RELAXED,
                                      __HIP_MEMORY_SCOPE_AGENT);
#pragma unroll 1
        for (int s = 1; s < SEGS; ++s) {
            float o[K_NEI];
#pragma unroll
            for (int j = 0; j < K_NEI; ++j) o[j] = nx[j];
            if (s + 1 < SEGS) {
#pragma unroll
                for (int j = 0; j < K_NEI; ++j)
                    nx[j] = __hip_atomic_load(p + (s + 1) * K_NEI + j,
                                              __ATOMIC_RELAXED,
                                              __HIP_MEMORY_SCOPE_AGENT);
            }
            merge9(R, o);
        }
        float sum = 0.f;
#pragma unroll
        for (int j = 0; j < K_NEI; ++j) sum += sqrtf(fmaxf(R[j], 0.f));
        out[q] = sum * (1.0f / 9.0f);
    }
}

// ---------------------------------------------------------------------------
extern "C" void kernel_launch(void* const* d_in, const int* in_sizes, int n_in,
                              void* d_out, int out_size, void* d_ws, size_t ws_size,
                              hipStream_t stream) {
    const float* feats = (const float*)d_in[0];   // [M, D]
    const float* bank  = (const float*)d_in[1];   // [N, D]

    char* w = (char*)d_ws;
    __hip_bfloat16* bankbf = (__hip_bfloat16*)w;                       // 16 MB
    __hip_bfloat16* featbf = (__hip_bfloat16*)(w + (size_t)N * D * 2); // 1 MB
    float* bsqn = (float*)(w + (size_t)(N + M) * D * 2);               // 256 KB
    float* qsqp = bsqn + N;                                            // 16 KB
    float* part = qsqp + M;                                            // 4.5 MB
    int*   thr_g = (int*)(part + (size_t)M * SEGS * K_NEI);            // 16 KB
    int*   done  = thr_g + M;                                          // 128 B
    float* out  = (float*)d_out;

    prep_kernel<<<(N + M) / 4, 256, 0, stream>>>(bank, feats, bankbf, featbf,
                                                 bsqn, qsqp, thr_g, done);
    knn_main<<<QGROUPS * SEGS, 256, 0, stream>>>(bankbf, featbf, bsqn, qsqp,
                                                 thr_g, part, done, out);
}